// Round 6
// baseline (80.742 us; speedup 1.0000x reference)
//
#include <hip/hip_runtime.h>

// Problem constants
#define CIN   16
#define COUT  32
#define BATCH 2
#define DSP   32
#define HSP   128
#define WSP   128
#define NVOX  (BATCH*DSP*HSP*WSP)   // 1,048,576 voxels

// conv tile: 4(z) x 4(y) x 32(x); halo patch 6 x 6 x 34
#define TZ 4
#define TY 4
#define TX 32
#define NTZ 8               // DSP/TZ
#define NTY 32              // HSP/TY
#define NTX 4               // WSP/TX
#define NTILES (BATCH*NTZ*NTY*NTX)   // 2048
#define PZ 6
#define PYY 6
#define PXX 34
#define PVOX (PZ*PYY*PXX)   // 1224
#define HALFU (PVOX*8)      // ushort units per ci-half (9792 = 19584 B)
#define NPAIR 14            // 27 taps -> 14 K=32 pairs (last padded with zero weights)
#define NWREP ((NPAIR*2*64*8 + 255)/256)   // 56 repack blocks

typedef __bf16 bf16x8 __attribute__((ext_vector_type(8)));
typedef float  f32x4  __attribute__((ext_vector_type(4)));

// ---- fused: dedup (last-write-wins via atomicMax) + weight repack ----
// wpack flat idx = ((pair*2 + half)*64 + lane)*8 + j
// tap = 2*pair + ((lane>>4)>>1), ci = ((lane>>4)&1)*8 + j, cout = half*16 + (lane&15)
__global__ void k_prep(const int4* __restrict__ coords, int n, int nbDedup,
                       int* __restrict__ map,
                       const float* __restrict__ w, __bf16* __restrict__ wpack) {
    int bb = blockIdx.x;
    if (bb < nbDedup) {
        int p = bb * 256 + threadIdx.x;
        if (p >= n) return;
        int4 c = coords[p];
        int vox = ((c.x*DSP + c.y)*HSP + c.z)*WSP + c.w;
        atomicMax(&map[vox], p);
    } else {
        int i = (bb - nbDedup) * 256 + threadIdx.x;   // 14336 total
        if (i >= NPAIR*2*64*8) return;
        int j = i & 7, l = (i>>3) & 63, h = (i>>9) & 1, p = i >> 10;
        int tap = 2*p + ((l>>4)>>1);
        int co  = h*16 + (l & 15);
        int ci  = ((l>>4)&1)*8 + j;
        float v = (tap < 27) ? w[(co*CIN + ci)*27 + tap] : 0.0f;
        wpack[i] = (__bf16)v;
    }
}

// ---- winners write their bf16 feature vector into the dense grid ----
__global__ void k_scatter(const int4* __restrict__ coords, const int* __restrict__ map,
                          const float* __restrict__ feat, __bf16* __restrict__ dense,
                          int n) {
    int p = blockIdx.x * 256 + threadIdx.x;
    if (p >= n) return;
    int4 c = coords[p];
    int vox = ((c.x*DSP + c.y)*HSP + c.z)*WSP + c.w;
    if (map[vox] != p) return;                        // only last-writer survives
    const float4* fp = (const float4*)(feat + (size_t)p*CIN);
    float4 f0 = fp[0], f1 = fp[1], f2 = fp[2], f3 = fp[3];
    bf16x8 lo = { (__bf16)f0.x,(__bf16)f0.y,(__bf16)f0.z,(__bf16)f0.w,
                  (__bf16)f1.x,(__bf16)f1.y,(__bf16)f1.z,(__bf16)f1.w };
    bf16x8 hi = { (__bf16)f2.x,(__bf16)f2.y,(__bf16)f2.z,(__bf16)f2.w,
                  (__bf16)f3.x,(__bf16)f3.y,(__bf16)f3.z,(__bf16)f3.w };
    __bf16* d = dense + (size_t)vox*CIN;
    *(bf16x8*)d       = lo;
    *(bf16x8*)(d + 8) = hi;
}

// ---------------- dense tiled conv (MFMA), fully regular ----------------
__global__ __launch_bounds__(256, 4) void k_conv(
    const __bf16* __restrict__ dense, const __bf16* __restrict__ wpack,
    const float* __restrict__ bias, float* __restrict__ out)
{
    __shared__ __align__(16) ushort patch[2*HALFU];   // 39168 B (lo | hi ci-halves)

    int tile = blockIdx.x;
    int txi = tile & 3;
    int tyi = (tile >> 2) & 31;
    int tzi = (tile >> 7) & 7;
    int b   = tile >> 10;
    int z0 = tzi*TZ, y0 = tyi*TY, x0 = txi*TX;

    int tid  = threadIdx.x;
    int lane = tid & 63, wave = tid >> 6;
    int lx16  = lane & 15;
    int lhalf = (lane >> 4) & 1;
    int ltp   = (lane >> 4) >> 1;

    // per-lane patch voxel offsets per tap-pair
    int voff[NPAIR];
    #pragma unroll
    for (int p = 0; p < NPAIR; ++p) {
        int tap = 2*p + ltp; if (tap > 26) tap = 26;   // A read in-bounds; B zero there
        int kd = tap/9, kh = (tap/3)%3, kw = tap%3;
        voff[p] = (kd*PYY + kh)*PXX + kw;
    }
    float bv0 = bias[lx16], bv1 = bias[16 + lx16];

    // ---- patch load: coalesced global->LDS copy with zero-fill borders ----
    // u indexes (voxel v, ci-half h): u = v*2 + h -> consecutive 16B global chunks
    for (int u = tid; u < 2*PVOX; u += 256) {
        int v  = u >> 1, h = u & 1;
        int pz = v / (PYY*PXX);
        int rem = v - pz*(PYY*PXX);
        int py = rem / PXX;
        int px = rem - py*PXX;
        int gz = z0 - 1 + pz, gy = y0 - 1 + py, gx = x0 - 1 + px;
        uint4 val = make_uint4(0,0,0,0);
        if ((unsigned)gz < DSP && (unsigned)gy < HSP && (unsigned)gx < WSP) {
            size_t vox = (((size_t)b*DSP + gz)*HSP + gy)*WSP + gx;
            val = ((const uint4*)(dense + vox*CIN))[h];
        }
        *(uint4*)(patch + h*HALFU + v*8) = val;
    }
    __syncthreads();

    // ---- compute: pair-outer / group-inner, 1-deep weight prefetch ----
    // wave = z (4 layers); gi -> y = gi>>1 (4 rows), xg = gi&1 (two 16x groups)
    f32x4 acc[8][2];
    #pragma unroll
    for (int gi = 0; gi < 8; ++gi) {
        acc[gi][0] = (f32x4){0.f,0.f,0.f,0.f};
        acc[gi][1] = (f32x4){0.f,0.f,0.f,0.f};
    }
    const ushort* pb = patch + lhalf*HALFU + ((wave*PYY)*PXX + lx16)*8;
    bf16x8 w0 = *(const bf16x8*)(wpack + (size_t)(0*64 + lane)*8);
    bf16x8 w1 = *(const bf16x8*)(wpack + (size_t)(1*64 + lane)*8);
    #pragma unroll
    for (int p = 0; p < NPAIR; ++p) {
        int pn = (p + 1 < NPAIR) ? p + 1 : 0;          // last prefetch harmless
        bf16x8 nw0 = *(const bf16x8*)(wpack + (size_t)((pn*2+0)*64 + lane)*8);
        bf16x8 nw1 = *(const bf16x8*)(wpack + (size_t)((pn*2+1)*64 + lane)*8);
        const ushort* pa = pb + voff[p]*8;
        #pragma unroll
        for (int gi = 0; gi < 8; ++gi) {
            int y = gi >> 1, xg = gi & 1;
            bf16x8 a = *(const bf16x8*)(pa + (y*PXX + xg*16)*8);
            acc[gi][0] = __builtin_amdgcn_mfma_f32_16x16x32_bf16(a, w0, acc[gi][0], 0,0,0);
            acc[gi][1] = __builtin_amdgcn_mfma_f32_16x16x32_bf16(a, w1, acc[gi][1], 0,0,0);
        }
        w0 = nw0; w1 = nw1;
    }

    // ---- writeback: full 128B lines per (cout,z,y) row (xg=0,1 adjacent) ----
    // D col = lane&15 = cout-in-half, row = (lane>>4)*4+reg = x-in-group
    #pragma unroll
    for (int gi = 0; gi < 8; ++gi) {
        int y = gi >> 1, xg = gi & 1;
        int gz = z0 + wave, gy = y0 + y, gx = x0 + xg*16 + ((lane >> 4) << 2);
        f32x4 o0, o1;
        o0[0] = fmaxf(acc[gi][0][0]+bv0, 0.f); o0[1] = fmaxf(acc[gi][0][1]+bv0, 0.f);
        o0[2] = fmaxf(acc[gi][0][2]+bv0, 0.f); o0[3] = fmaxf(acc[gi][0][3]+bv0, 0.f);
        o1[0] = fmaxf(acc[gi][1][0]+bv1, 0.f); o1[1] = fmaxf(acc[gi][1][1]+bv1, 0.f);
        o1[2] = fmaxf(acc[gi][1][2]+bv1, 0.f); o1[3] = fmaxf(acc[gi][1][3]+bv1, 0.f);
        size_t base0 = ((((size_t)b*COUT + lx16)*DSP + gz)*HSP + gy)*WSP + gx;
        size_t base1 = base0 + (size_t)16*DSP*HSP*WSP;
        __builtin_nontemporal_store(o0, (f32x4*)(out + base0));
        __builtin_nontemporal_store(o1, (f32x4*)(out + base1));
    }
}

extern "C" void kernel_launch(void* const* d_in, const int* in_sizes, int n_in,
                              void* d_out, int out_size, void* d_ws, size_t ws_size,
                              hipStream_t stream) {
    const float* feat   = (const float*)d_in[0];
    const int4*  coords = (const int4*)d_in[1];
    const float* weight = (const float*)d_in[2];
    const float* bias   = (const float*)d_in[3];
    float* out = (float*)d_out;
    int n = in_sizes[0] / CIN;

    // workspace: map 4MB | dense 33.5MB | wpack 28KB
    int*    map   = (int*)d_ws;
    __bf16* dense = (__bf16*)(map + NVOX);
    __bf16* wpack = dense + (size_t)NVOX*CIN;

    hipMemsetAsync(map, 0xFF, (size_t)NVOX*sizeof(int), stream);
    hipMemsetAsync(dense, 0, (size_t)NVOX*CIN*sizeof(__bf16), stream);

    int nb = (n + 255) / 256;
    k_prep   <<<nb + NWREP, 256, 0, stream>>>(coords, n, nb, map, weight, wpack);
    k_scatter<<<nb, 256, 0, stream>>>(coords, map, feat, dense, n);
    k_conv   <<<NTILES, 256, 0, stream>>>(dense, wpack, bias, out);
}